// Round 16
// baseline (2428.563 us; speedup 1.0000x reference)
//
#include <hip/hip_runtime.h>
#include <math.h>

typedef _Float16 f16;
typedef f16 f16x8 __attribute__((ext_vector_type(8)));
typedef float f32x4 __attribute__((ext_vector_type(4)));

#define NT    16384
#define DIM   4096
#define NEXP  128
#define TOPK  8
#define NFLAT (NT * TOPK)   // 131072
#define SBLK  512
#define BT    64            // tokens per fused block (R9)
#define NFB   (NT / BT)     // 256
#define BK    64
#define NSTEP (DIM / BK)    // 64

// ---- workspace layout (bytes) ----
#define COUNTS_OFF 0
#define SEL_OFF    1024
#define WGT_OFF    (SEL_OFF + NFLAT * 4)
#define BH_OFF     (WGT_OFF + NFLAT * 4)
#define BO_OFF     (BH_OFF + NEXP * SBLK * 4)
#define WPK_OFF    (BO_OFF + NEXP * SBLK * 4)    // 2 MB packed W
#define SCR_OFF    (WPK_OFF + NEXP * DIM * 4)    // ablation sink (512 KB)

#define G1P __attribute__((address_space(1)))
#define L3P __attribute__((address_space(3)))

__device__ __forceinline__ void gload_lds16(const void* g, void* l) {
    __builtin_amdgcn_global_load_lds((const G1P unsigned int*)g,
                                     (L3P unsigned int*)l, 16, 0, 0);
}

__device__ __forceinline__ void split2(float v, f16& h, f16& m) {
    h = (f16)v;
    m = (f16)((v - (float)h) * 2048.0f);
}

// ============ prologue: pack 64*gw into fragment-ordered f16 chunks ============
__global__ __launch_bounds__(256)
void wsplit_kernel(const float* __restrict__ gw, char* __restrict__ wpk) {
    const int t = blockIdx.x * 256 + threadIdx.x;
    const int l = t & 63, kkc = (t >> 6) & 1, g = (t >> 7) & 7, st = t >> 10;
    const int e = g * 16 + (l & 15);
    const int k0 = st * 64 + kkc * 32 + (l >> 4) * 8;
    float4 a = *(const float4*)&gw[e * 4096 + k0];
    float4 b = *(const float4*)&gw[e * 4096 + k0 + 4];
    union { f16 f[8]; uint4 u; } ph, pm;
    split2(a.x * 64.f, ph.f[0], pm.f[0]); split2(a.y * 64.f, ph.f[1], pm.f[1]);
    split2(a.z * 64.f, ph.f[2], pm.f[2]); split2(a.w * 64.f, ph.f[3], pm.f[3]);
    split2(b.x * 64.f, ph.f[4], pm.f[4]); split2(b.y * 64.f, ph.f[5], pm.f[5]);
    split2(b.z * 64.f, ph.f[6], pm.f[6]); split2(b.w * 64.f, ph.f[7], pm.f[7]);
    const size_t base = ((size_t)(st * 8 + g) * 4 + kkc) * 1024 + l * 16;
    *(uint4*)(wpk + base)        = ph.u;
    *(uint4*)(wpk + base + 2048) = pm.u;
}

// ==================== REAL PIPELINE: R9 fused (118 us) verbatim ====================
__global__ __launch_bounds__(512, 2)
void fused_kernel(const float* __restrict__ x, const char* __restrict__ wpk,
                  float* __restrict__ wgt, int* __restrict__ sel,
                  int* __restrict__ counts, int* __restrict__ bh) {
    __shared__ __align__(16) char smem[98304];
    char* WB = smem + 32768;

    const int tid  = threadIdx.x;
    const int tok0 = blockIdx.x * BT;
    const int lane = tid & 63, wid = tid >> 6;
    const int r = wid >> 2, eg = wid & 3;
    const int fr = lane & 15, hi = lane >> 4;
    const int srow = tid >> 3;
    const int skq  = (tid & 7) * 8;
    const int xi = srow >> 4, xfr = srow & 15;
    const int xkk = skq >> 5, xhi = (skq >> 3) & 3;
    const int xslot = xhi * 16 + xfr;
    const int xwb = ((xi * 2 + xkk) * 64 + (xslot ^ ((xslot >> 4) << 1))) * 16;
    const int lxs = (lane ^ ((lane >> 4) << 1)) * 16;
    const int myg = 2 * eg + r;

    f32x4 acc0[2][2], acc1[2][2];
#pragma unroll
    for (int i = 0; i < 2; ++i)
#pragma unroll
        for (int j = 0; j < 2; ++j) {
            acc0[i][j] = (f32x4){0.f, 0.f, 0.f, 0.f};
            acc1[i][j] = (f32x4){0.f, 0.f, 0.f, 0.f};
        }

    const size_t xrow = (size_t)(tok0 + srow) * DIM;

#define X_PREF(RA, RB, SI) { \
    RA = *(const float4*)&x[xrow + (size_t)(SI) * BK + skq]; \
    RB = *(const float4*)&x[xrow + (size_t)(SI) * BK + skq + 4]; }
#define W_PREF(SI, B) { \
    const char* wsrc = wpk + ((size_t)(SI) * 8 + myg) * 4096 + lane * 16; \
    char* wdst = WB + (B) * 32768 + myg * 4096; \
    gload_lds16(wsrc,        wdst); \
    gload_lds16(wsrc + 1024, wdst + 1024); \
    gload_lds16(wsrc + 2048, wdst + 2048); \
    gload_lds16(wsrc + 3072, wdst + 3072); }
#define STAGE(CUR, RA, RB) { \
    union { f16 f[8]; f16x8 v; } ph, pm; \
    split2(RA.x, ph.f[0], pm.f[0]); split2(RA.y, ph.f[1], pm.f[1]); \
    split2(RA.z, ph.f[2], pm.f[2]); split2(RA.w, ph.f[3], pm.f[3]); \
    split2(RB.x, ph.f[4], pm.f[4]); split2(RB.y, ph.f[5], pm.f[5]); \
    split2(RB.z, ph.f[6], pm.f[6]); split2(RB.w, ph.f[7], pm.f[7]); \
    *(f16x8*)(smem + (CUR) * 8192 + xwb) = ph.v; \
    *(f16x8*)(smem + 16384 + (CUR) * 8192 + xwb) = pm.v; }
#define COMPUTE(CUR) { \
    _Pragma("unroll") \
    for (int kk = 0; kk < 2; ++kk) { \
        f16x8 ah[2], am[2]; \
        _Pragma("unroll") \
        for (int i = 0; i < 2; ++i) { \
            const int xb = (CUR) * 8192 + ((2 * r + i) * 2 + kk) * 1024 + lxs; \
            ah[i] = *(const f16x8*)(smem + xb); \
            am[i] = *(const f16x8*)(smem + 16384 + xb); \
        } \
        _Pragma("unroll") \
        for (int j = 0; j < 2; ++j) { \
            const int wb = (CUR) * 32768 + (2 * eg + j) * 4096 + kk * 1024 + lane * 16; \
            f16x8 bhf = *(const f16x8*)(WB + wb); \
            f16x8 bmf = *(const f16x8*)(WB + wb + 2048); \
            _Pragma("unroll") \
            for (int i = 0; i < 2; ++i) { \
                acc0[i][j] = __builtin_amdgcn_mfma_f32_16x16x32_f16(ah[i], bhf, acc0[i][j], 0, 0, 0); \
                acc1[i][j] = __builtin_amdgcn_mfma_f32_16x16x32_f16(ah[i], bmf, acc1[i][j], 0, 0, 0); \
                acc1[i][j] = __builtin_amdgcn_mfma_f32_16x16x32_f16(am[i], bhf, acc1[i][j], 0, 0, 0); \
            } \
        } \
    } }
#define STEP(CUR, RA, RB, PX, PW, SI, VMSTR) { \
    STAGE(CUR, RA, RB); \
    asm volatile("s_waitcnt lgkmcnt(0) vmcnt(" VMSTR ")" ::: "memory"); \
    __builtin_amdgcn_s_barrier(); \
    if (PW) { W_PREF((SI) + 1, (CUR) ^ 1); } \
    __builtin_amdgcn_sched_barrier(0); \
    if (PX) { X_PREF(RA, RB, (SI) + 2); } \
    __builtin_amdgcn_s_setprio(1); \
    COMPUTE(CUR); \
    __builtin_amdgcn_s_setprio(0); }

    float4 a0, b0, a1, b1;
    W_PREF(0, 0);
    X_PREF(a0, b0, 0);
    X_PREF(a1, b1, 1);

    for (int st = 0; st < 62; st += 2) {
        STEP(0, a0, b0, 1, 1, st, "2");
        STEP(1, a1, b1, 1, 1, st + 1, "2");
    }
    STEP(0, a0, b0, 0, 1, 62, "2");
    STEP(1, a1, b1, 0, 0, 63, "0");

    __syncthreads();

    float* S  = (float*)smem;
    int*   h2 = (int*)(smem + 34816);
#pragma unroll
    for (int i = 0; i < 2; ++i)
#pragma unroll
        for (int j = 0; j < 2; ++j)
#pragma unroll
            for (int q = 0; q < 4; ++q) {
                int t = r * 32 + i * 16 + hi * 4 + q;
                int e = eg * 32 + j * 16 + fr;
                S[t * 129 + e] =
                    (acc0[i][j][q] + acc1[i][j][q] * (1.0f / 2048.0f)) * (1.0f / 64.0f);
            }
    if (tid < 256) h2[tid] = 0;
    __syncthreads();

    if (tid < BT) {
        float bs[8]; int bi[8];
#pragma unroll
        for (int q = 0; q < 8; ++q) { bs[q] = -3.0e38f; bi[q] = 0; }
        for (int e = 0; e < NEXP; ++e) {
            float s = S[tid * 129 + e];
            if (s > bs[7]) {
                int pos = 7;
#pragma unroll
                for (int q = 6; q >= 0; q--) pos = (s > bs[q]) ? q : pos;
#pragma unroll
                for (int q = 7; q >= 1; q--) {
                    bool sh = (q > pos);
                    bs[q] = sh ? bs[q - 1] : bs[q];
                    bi[q] = sh ? bi[q - 1] : bi[q];
                }
#pragma unroll
                for (int q = 0; q < 8; q++)
                    if (q == pos) { bs[q] = s; bi[q] = e; }
            }
        }
        float m = bs[0], sum = 0.f, ex[8];
#pragma unroll
        for (int q = 0; q < 8; ++q) { ex[q] = expf(bs[q] - m); sum += ex[q]; }
        float inv = 1.f / fmaxf(sum, 1e-8f);
        const int tok = tok0 + tid;
#pragma unroll
        for (int q = 0; q < 8; ++q) {
            wgt[tok * TOPK + q] = ex[q] * inv;
            sel[tok * TOPK + q] = bi[q];
            atomicAdd(&h2[(tid >> 5) * NEXP + bi[q]], 1);
        }
    }
    __syncthreads();
    if (tid < NEXP) {
        int c0 = h2[tid], c1 = h2[NEXP + tid];
        bh[tid * SBLK + 2 * blockIdx.x]     = c0;
        bh[tid * SBLK + 2 * blockIdx.x + 1] = c1;
        if (c0 + c1) atomicAdd(&counts[tid], c0 + c1);
    }
}

// ==================== ABLATION: R9 step, phases gated by MODE ====================
#define AB_BAR  1
#define AB_MFMA 2
#define AB_DS   4
#define AB_X    8
#define REPS    8

template <int MODE>
__global__ __launch_bounds__(512, 1)
void abl_kernel(const float* __restrict__ x, const char* __restrict__ wpk,
                float* __restrict__ scratch) {
    __shared__ __align__(16) char smem[98304];
    char* WB = smem + 32768;

    const int tid  = threadIdx.x;
    const int tok0 = blockIdx.x * BT;
    const int lane = tid & 63, wid = tid >> 6;
    const int r = wid >> 2, eg = wid & 3;
    const int srow = tid >> 3;
    const int skq  = (tid & 7) * 8;
    const int xi = srow >> 4, xfr = srow & 15;
    const int xkk = skq >> 5, xhi = (skq >> 3) & 3;
    const int xslot = xhi * 16 + xfr;
    const int xwb = ((xi * 2 + xkk) * 64 + (xslot ^ ((xslot >> 4) << 1))) * 16;
    const int lxs = (lane ^ ((lane >> 4) << 1)) * 16;
    const int myg = 2 * eg + r;

    f32x4 acc0[2][2], acc1[2][2];
#pragma unroll
    for (int i = 0; i < 2; ++i)
#pragma unroll
        for (int j = 0; j < 2; ++j) {
            acc0[i][j] = (f32x4){0.f, 0.f, 0.f, 0.f};
            acc1[i][j] = (f32x4){0.f, 0.f, 0.f, 0.f};
        }
    unsigned iacc = 0;

    const size_t xrow = (size_t)(tok0 + srow) * DIM;
    float4 a0, b0, a1, b1;

#define AXL(RA, RB, SI) { \
    RA = *(const float4*)&x[xrow + (size_t)(SI) * BK + skq]; \
    RB = *(const float4*)&x[xrow + (size_t)(SI) * BK + skq + 4]; }
#define AWP(SI, B) { \
    const char* ws_ = wpk + ((size_t)(SI) * 8 + myg) * 4096 + lane * 16; \
    char* wd_ = WB + (B) * 32768 + myg * 4096; \
    gload_lds16(ws_,        wd_); \
    gload_lds16(ws_ + 1024, wd_ + 1024); \
    gload_lds16(ws_ + 2048, wd_ + 2048); \
    gload_lds16(ws_ + 3072, wd_ + 3072); }
#define ABSTEP(CUR, RA, RB, PX, PW, SI, VMSTR) { \
    union { f16 f[8]; f16x8 v; } ph_, pm_; \
    if constexpr (MODE & AB_X) { \
        split2(RA.x, ph_.f[0], pm_.f[0]); split2(RA.y, ph_.f[1], pm_.f[1]); \
        split2(RA.z, ph_.f[2], pm_.f[2]); split2(RA.w, ph_.f[3], pm_.f[3]); \
        split2(RB.x, ph_.f[4], pm_.f[4]); split2(RB.y, ph_.f[5], pm_.f[5]); \
        split2(RB.z, ph_.f[6], pm_.f[6]); split2(RB.w, ph_.f[7], pm_.f[7]); \
        *(f16x8*)(smem + (CUR) * 8192 + xwb) = ph_.v; \
        *(f16x8*)(smem + 16384 + (CUR) * 8192 + xwb) = pm_.v; \
    } else { \
        _Pragma("unroll") \
        for (int z = 0; z < 8; ++z) { ph_.f[z] = (f16)1.0f; pm_.f[z] = (f16)0.5f; } \
    } \
    asm volatile("s_waitcnt lgkmcnt(0) vmcnt(" VMSTR ")" ::: "memory"); \
    if constexpr (MODE & AB_BAR) __builtin_amdgcn_s_barrier(); \
    if (PW) { AWP((SI) + 1, (CUR) ^ 1); } \
    __builtin_amdgcn_sched_barrier(0); \
    if constexpr (MODE & AB_X) { if (PX) { AXL(RA, RB, (SI) + 2); } } \
    __builtin_amdgcn_s_setprio(1); \
    _Pragma("unroll") \
    for (int kk = 0; kk < 2; ++kk) { \
        f16x8 ah_[2], am_[2]; \
        if constexpr (MODE & AB_DS) { \
            _Pragma("unroll") \
            for (int i = 0; i < 2; ++i) { \
                const int xb = (CUR) * 8192 + ((2 * r + i) * 2 + kk) * 1024 + lxs; \
                ah_[i] = *(const f16x8*)(smem + xb); \
                am_[i] = *(const f16x8*)(smem + 16384 + xb); \
            } \
        } else { ah_[0] = ph_.v; ah_[1] = pm_.v; am_[0] = ph_.v; am_[1] = pm_.v; } \
        _Pragma("unroll") \
        for (int j = 0; j < 2; ++j) { \
            f16x8 bh_, bm_; \
            if constexpr (MODE & AB_DS) { \
                const int wb_ = (CUR) * 32768 + (2 * eg + j) * 4096 + kk * 1024 + lane * 16; \
                bh_ = *(const f16x8*)(WB + wb_); \
                bm_ = *(const f16x8*)(WB + wb_ + 2048); \
            } else { bh_ = ph_.v; bm_ = pm_.v; } \
            if constexpr (MODE & AB_MFMA) { \
                _Pragma("unroll") \
                for (int i = 0; i < 2; ++i) { \
                    acc0[i][j] = __builtin_amdgcn_mfma_f32_16x16x32_f16(ah_[i], bh_, acc0[i][j], 0, 0, 0); \
                    acc1[i][j] = __builtin_amdgcn_mfma_f32_16x16x32_f16(ah_[i], bm_, acc1[i][j], 0, 0, 0); \
                    acc1[i][j] = __builtin_amdgcn_mfma_f32_16x16x32_f16(am_[i], bh_, acc1[i][j], 0, 0, 0); \
                } \
            } else { \
                _Pragma("unroll") \
                for (int i = 0; i < 2; ++i) { \
                    iacc ^= ((const unsigned*)&ah_[i])[0] ^ ((const unsigned*)&ah_[i])[3]; \
                    iacc ^= ((const unsigned*)&am_[i])[0] ^ ((const unsigned*)&am_[i])[3]; \
                } \
                iacc ^= ((const unsigned*)&bh_)[0] ^ ((const unsigned*)&bh_)[3]; \
                iacc ^= ((const unsigned*)&bm_)[0] ^ ((const unsigned*)&bm_)[3]; \
            } \
        } \
    } \
    __builtin_amdgcn_s_setprio(0); }

    for (int rep = 0; rep < REPS; ++rep) {
        AWP(0, 0);
        if constexpr (MODE & AB_X) { AXL(a0, b0, 0); AXL(a1, b1, 1); }
        for (int st = 0; st < 62; st += 2) {
            ABSTEP(0, a0, b0, 1, 1, st, "2");
            ABSTEP(1, a1, b1, 1, 1, st + 1, "2");
        }
        ABSTEP(0, a0, b0, 0, 1, 62, "2");
        ABSTEP(1, a1, b1, 0, 0, 63, "0");
        asm volatile("s_waitcnt vmcnt(0) lgkmcnt(0)" ::: "memory");
        if constexpr (MODE & AB_BAR) __builtin_amdgcn_s_barrier();
    }

    float s = (float)iacc;
#pragma unroll
    for (int i = 0; i < 2; ++i)
#pragma unroll
        for (int j = 0; j < 2; ++j)
#pragma unroll
            for (int q = 0; q < 4; ++q) s += acc0[i][j][q] + acc1[i][j][q];
    scratch[(size_t)blockIdx.x * 512 + tid] = s;
}

// ============ scan + scatter (R9 verbatim) ============
__global__ void scan_kernel(const int* __restrict__ bh, const int* __restrict__ counts,
                            int* __restrict__ bo, float* __restrict__ out) {
    const int e = blockIdx.x, tid = threadIdx.x;
    __shared__ int pre[NEXP];
    __shared__ int wsum[8];
    if (tid < NEXP) pre[tid] = counts[tid];
    __syncthreads();
#pragma unroll
    for (int d = 1; d < NEXP; d <<= 1) {
        int o = (tid < NEXP && tid >= d) ? pre[tid - d] : 0;
        __syncthreads();
        if (tid < NEXP) pre[tid] += o;
        __syncthreads();
    }
    const int gb = (e == 0) ? 0 : pre[e - 1];
    if (tid == 0) out[2 * NFLAT + e] = (float)counts[e];

    const int lane = tid & 63, wid = tid >> 6;
    int v = bh[e * SBLK + tid];
    int sc = v;
#pragma unroll
    for (int d = 1; d < 64; d <<= 1) {
        int o = __shfl_up(sc, d);
        sc += (lane >= d) ? o : 0;
    }
    if (lane == 63) wsum[wid] = sc;
    __syncthreads();
    int add = 0;
#pragma unroll
    for (int ww = 0; ww < 8; ww++) add += (ww < wid) ? wsum[ww] : 0;
    bo[e * SBLK + tid] = gb + sc - v + add;
}

__global__ void scatter_kernel(const int* __restrict__ sel, const float* __restrict__ wgt,
                               const int* __restrict__ bo, float* __restrict__ out) {
    const int tid = threadIdx.x, b = blockIdx.x;
    const int i = b * 256 + tid;
    const int e = sel[i];
    const int lane = tid & 63, wid = tid >> 6;
    unsigned long long m = ~0ull;
#pragma unroll
    for (int bit = 0; bit < 7; bit++) {
        unsigned long long bal = __ballot((e >> bit) & 1);
        m &= ((e >> bit) & 1) ? bal : ~bal;
    }
    unsigned long long lower = (lane == 0) ? 0ull : (~0ull >> (64 - lane));
    int wrank = __popcll(m & lower);

    __shared__ int wh_[4][NEXP];
    ((int*)wh_)[tid] = 0; ((int*)wh_)[tid + 256] = 0;
    __syncthreads();
    if (wrank == 0) wh_[wid][e] = __popcll(m);
    __syncthreads();
    int off = 0;
#pragma unroll
    for (int ww = 0; ww < 4; ww++) off += (ww < wid) ? wh_[ww][e] : 0;

    int pos = bo[e * SBLK + b] + off + wrank;
    out[pos] = wgt[i];
    out[NFLAT + pos] = (float)(i >> 3);
}

extern "C" void kernel_launch(void* const* d_in, const int* in_sizes, int n_in,
                              void* d_out, int out_size, void* d_ws, size_t ws_size,
                              hipStream_t stream) {
    const float* x  = (const float*)d_in[0];
    const float* gw = (const float*)d_in[1];
    float* out = (float*)d_out;
    char*  ws  = (char*)d_ws;

    int*   counts = (int*)(ws + COUNTS_OFF);
    int*   sel    = (int*)(ws + SEL_OFF);
    float* wgt    = (float*)(ws + WGT_OFF);
    int*   bh     = (int*)(ws + BH_OFF);
    int*   bo     = (int*)(ws + BO_OFF);
    char*  wpk    = ws + WPK_OFF;
    float* scr    = (float*)(ws + SCR_OFF);

    hipMemsetAsync(counts, 0, NEXP * sizeof(int), stream);

    // real pipeline (R9, correct output)
    wsplit_kernel<<<256, 256, 0, stream>>>(gw, wpk);
    fused_kernel<<<NFB, 512, 0, stream>>>(x, wpk, wgt, sel, counts, bh);
    scan_kernel<<<NEXP, 512, 0, stream>>>(bh, counts, bo, out);
    scatter_kernel<<<SBLK, 256, 0, stream>>>(sel, wgt, bo, out);

    // ablation probes (write only to scratch; timings read from rocprof table)
    abl_kernel<15><<<NFB, 512, 0, stream>>>(x, wpk, scr);  // A: full
    abl_kernel<14><<<NFB, 512, 0, stream>>>(x, wpk, scr);  // B: no barrier
    abl_kernel<13><<<NFB, 512, 0, stream>>>(x, wpk, scr);  // C: no MFMA
    abl_kernel<11><<<NFB, 512, 0, stream>>>(x, wpk, scr);  // D: no ds_read
    abl_kernel<7> <<<NFB, 512, 0, stream>>>(x, wpk, scr);  // E: no X-path
}

// Round 17
// 130.338 us; speedup vs baseline: 18.6328x; 18.6328x over previous
//
#include <hip/hip_runtime.h>
#include <math.h>

typedef _Float16 f16;
typedef f16 f16x8 __attribute__((ext_vector_type(8)));
typedef float f32x4 __attribute__((ext_vector_type(4)));

#define NT    16384
#define DIM   4096
#define NEXP  128
#define TOPK  8
#define NFLAT (NT * TOPK)   // 131072
#define SBLK  512           // sort blocks (256 sel entries each)
#define KS    2             // split-K
#define KPER  (DIM / KS)    // 2048
#define BK    32
#define NST   (KPER / BK)   // 64 steps per block
#define BT    64            // tokens per gemm block

// ---- workspace layout (bytes) ----
#define COUNTS_OFF 0
#define SEL_OFF    1024
#define WGT_OFF    (SEL_OFF + NFLAT * 4)
#define BH_OFF     (WGT_OFF + NFLAT * 4)
#define BO_OFF     (BH_OFF + NEXP * SBLK * 4)
#define WPK_OFF    (BO_OFF + NEXP * SBLK * 4)    // 2 MB packed W
#define PART_OFF   (WPK_OFF + NEXP * DIM * 4)    // 16.8 MB partials

#define G1P __attribute__((address_space(1)))
#define L3P __attribute__((address_space(3)))

__device__ __forceinline__ void gload_lds16(const void* g, void* l) {
    // LDS dest = wave-uniform base + lane*16 (HW); global src = per-lane
    __builtin_amdgcn_global_load_lds((const G1P unsigned int*)g,
                                     (L3P unsigned int*)l, 16, 0, 0);
}

// fp32 -> fp16 high + scaled residual (next ~11 mantissa bits, normal range)
__device__ __forceinline__ void split2(float v, f16& h, f16& m) {
    h = (f16)v;
    m = (f16)((v - (float)h) * 2048.0f);
}

// ============ prologue: pack 64*gw into BK=32 fragment chunks ============
// wpk[(st*8+g)*2048 + {0:h,1024:m} + lane*16], st 0..127, g 0..7.
// content(lane l) = halves of 64*gw[g*16+(l&15)][st*32 + (l>>4)*8 ..+7]
__global__ __launch_bounds__(256)
void wsplit_kernel(const float* __restrict__ gw, char* __restrict__ wpk) {
    const int t = blockIdx.x * 256 + threadIdx.x;    // 65536 threads
    const int l = t & 63, g = (t >> 6) & 7, st = t >> 9;
    const int e = g * 16 + (l & 15);
    const int k0 = st * 32 + (l >> 4) * 8;
    float4 a = *(const float4*)&gw[e * 4096 + k0];
    float4 b = *(const float4*)&gw[e * 4096 + k0 + 4];
    union { f16 f[8]; uint4 u; } ph, pm;
    split2(a.x * 64.f, ph.f[0], pm.f[0]); split2(a.y * 64.f, ph.f[1], pm.f[1]);
    split2(a.z * 64.f, ph.f[2], pm.f[2]); split2(a.w * 64.f, ph.f[3], pm.f[3]);
    split2(b.x * 64.f, ph.f[4], pm.f[4]); split2(b.y * 64.f, ph.f[5], pm.f[5]);
    split2(b.z * 64.f, ph.f[6], pm.f[6]); split2(b.w * 64.f, ph.f[7], pm.f[7]);
    const size_t base = (size_t)(st * 8 + g) * 2048 + l * 16;
    *(uint4*)(wpk + base)        = ph.u;
    *(uint4*)(wpk + base + 1024) = pm.u;
}

// ============ GEMM: partial[ks][tok][e] @ 16 waves/CU (4/SIMD) ============
// 512 blocks = 256 token-tiles x 2 K-slices; 512 thr = 8 waves
// (2 tok-grp x 4 exp-grp); wave tile 32 tok x 32 exp; 64 K-steps of 32.
// LDS 48KB -> 2 blocks/CU: X h/m frag-major swizzled dbuf (16K) +
// W dbuf (32K, per-wave own-group gload_lds). One barrier + vmcnt(1)/step.
__global__ __launch_bounds__(512, 4)
void gemm_kernel(const float* __restrict__ x, const char* __restrict__ wpk,
                 float* __restrict__ partial) {
    __shared__ __align__(16) char smem[49152];
    char* WB = smem + 16384;

    const int tid  = threadIdx.x;
    const int bid  = blockIdx.x;
    const int ks   = bid & 1;
    const int tok0 = (bid >> 1) * BT;
    const int lane = tid & 63, wid = tid >> 6;
    const int r = wid >> 2, eg = wid & 3;      // tok-group (32), expert-group (32)
    const int fr = lane & 15, hi = lane >> 4;

    // X staging: thread -> row tid>>3 (0..63), k-chunk (tid&7)*4 (0..28)
    const int srow = tid >> 3;
    const int xi  = srow >> 4;                 // cell 0..3
    const int khi = (tid & 7) >> 1;            // 0..3
    const int xo  = tid & 1;                   // 8B half of the 16B slot
    const int slot = khi * 16 + (srow & 15);
    const int xwb = xi * 1024 + (slot ^ ((slot >> 4) << 1)) * 16 + xo * 8;
    const int lxs = (lane ^ ((lane >> 4) << 1)) * 16;   // swizzled read slot

    f32x4 acc0[2][2], acc1[2][2];
#pragma unroll
    for (int i = 0; i < 2; ++i)
#pragma unroll
        for (int j = 0; j < 2; ++j) {
            acc0[i][j] = (f32x4){0.f, 0.f, 0.f, 0.f};
            acc1[i][j] = (f32x4){0.f, 0.f, 0.f, 0.f};
        }

    const float* xbase = x + (size_t)(tok0 + srow) * DIM + ks * KPER + (tid & 7) * 4;
    const char*  bsrc0 = wpk + (size_t)(ks * NST * 8) * 2048 + lane * 16;

#define XLOAD(XR, ST) { XR = *(const float4*)(xbase + (size_t)(ST) * BK); }
// wave wid loads group g=wid's h+m chunk (2 x 1KB, lane-linear)
#define W_PREF(ST, B) { \
    const char* wsrc = bsrc0 + (size_t)((ST) * 8 + wid) * 2048; \
    char* wdst = WB + (B) * 16384 + wid * 2048; \
    gload_lds16(wsrc,        wdst); \
    gload_lds16(wsrc + 1024, wdst + 1024); }
#define STAGE(CUR, XR) { \
    union { f16 f[4]; uint2 u; } ph, pm; \
    split2(XR.x, ph.f[0], pm.f[0]); split2(XR.y, ph.f[1], pm.f[1]); \
    split2(XR.z, ph.f[2], pm.f[2]); split2(XR.w, ph.f[3], pm.f[3]); \
    *(uint2*)(smem + (CUR) * 4096 + xwb) = ph.u; \
    *(uint2*)(smem + 8192 + (CUR) * 4096 + xwb) = pm.u; }
#define COMPUTE(CUR) { \
    f16x8 ah[2], am[2]; \
    _Pragma("unroll") \
    for (int i = 0; i < 2; ++i) { \
        const int xb = (CUR) * 4096 + (r * 2 + i) * 1024 + lxs; \
        ah[i] = *(const f16x8*)(smem + xb); \
        am[i] = *(const f16x8*)(smem + 8192 + xb); \
    } \
    _Pragma("unroll") \
    for (int j = 0; j < 2; ++j) { \
        const char* bp = WB + (CUR) * 16384 + (2 * eg + j) * 2048 + lane * 16; \
        f16x8 bhf = *(const f16x8*)bp; \
        f16x8 bmf = *(const f16x8*)(bp + 1024); \
        _Pragma("unroll") \
        for (int i = 0; i < 2; ++i) { \
            acc0[i][j] = __builtin_amdgcn_mfma_f32_16x16x32_f16(ah[i], bhf, acc0[i][j], 0, 0, 0); \
            acc1[i][j] = __builtin_amdgcn_mfma_f32_16x16x32_f16(ah[i], bmf, acc1[i][j], 0, 0, 0); \
            acc1[i][j] = __builtin_amdgcn_mfma_f32_16x16x32_f16(am[i], bhf, acc1[i][j], 0, 0, 0); \
        } \
    } }
// Steady-state queue entering STAGE(st): [x[st], W[st](2), x[st+1]].
// STAGE's compiler wait retires x[st]; explicit vmcnt(1) retires W[st]
// (landed in LDS[cur]) keeping x[st+1]; post-barrier issues W[st+1](2)
// then x[st+2].
#define STEP(CUR, XR, PX, PW, SI, VMSTR) { \
    STAGE(CUR, XR); \
    asm volatile("s_waitcnt lgkmcnt(0) vmcnt(" VMSTR ")" ::: "memory"); \
    __builtin_amdgcn_s_barrier(); \
    __builtin_amdgcn_sched_barrier(0); \
    if (PW) { W_PREF((SI) + 1, (CUR) ^ 1); } \
    if (PX) { XLOAD(XR, (SI) + 2); } \
    __builtin_amdgcn_s_setprio(1); \
    COMPUTE(CUR); \
    __builtin_amdgcn_s_setprio(0); }

    float4 xr0, xr1;
    W_PREF(0, 0);
    XLOAD(xr0, 0);
    XLOAD(xr1, 1);

    for (int st = 0; st < 62; st += 2) {
        STEP(0, xr0, 1, 1, st, "1");
        STEP(1, xr1, 1, 1, st + 1, "1");
    }
    STEP(0, xr0, 0, 1, 62, "1");
    STEP(1, xr1, 0, 0, 63, "0");

    // epilogue: undo w*64 and m*2048 scales; write partial[ks][tok][e]
    float* pbase = partial + ((size_t)ks * NT + tok0 + r * 32) * NEXP;
#pragma unroll
    for (int i = 0; i < 2; ++i)
#pragma unroll
        for (int j = 0; j < 2; ++j)
#pragma unroll
            for (int q = 0; q < 4; ++q) {
                const int row = i * 16 + hi * 4 + q;
                const int e   = eg * 32 + j * 16 + fr;
                pbase[(size_t)row * NEXP + e] =
                    (acc0[i][j][q] + acc1[i][j][q] * (1.0f / 2048.0f)) * (1.0f / 64.0f);
            }
}

// ============ reduce + top-8 + softmax + sel/wgt/counts/blockhist ============
__global__ __launch_bounds__(256)
void topk_kernel(const float* __restrict__ partial, float* __restrict__ wgt,
                 int* __restrict__ sel, int* __restrict__ counts,
                 int* __restrict__ bh) {
    __shared__ float S[32][132];
    __shared__ int h[NEXP];
    const int tid = threadIdx.x;
    const int tok0 = blockIdx.x * 32;
    const int tok = tid >> 3, c = tid & 7;

    f32x4 s0 = {0, 0, 0, 0}, s1 = {0, 0, 0, 0}, s2 = {0, 0, 0, 0}, s3 = {0, 0, 0, 0};
#pragma unroll
    for (int ksq = 0; ksq < KS; ++ksq) {
        const float* p = partial + ((size_t)ksq * NT + tok0 + tok) * NEXP + c * 16;
        s0 += *(const f32x4*)(p);
        s1 += *(const f32x4*)(p + 4);
        s2 += *(const f32x4*)(p + 8);
        s3 += *(const f32x4*)(p + 12);
    }
    *(f32x4*)&S[tok][c * 16]      = s0;
    *(f32x4*)&S[tok][c * 16 + 4]  = s1;
    *(f32x4*)&S[tok][c * 16 + 8]  = s2;
    *(f32x4*)&S[tok][c * 16 + 12] = s3;
    if (tid < NEXP) h[tid] = 0;
    __syncthreads();

    if (tid < 32) {
        float bs[8]; int bi[8];
#pragma unroll
        for (int q = 0; q < 8; ++q) { bs[q] = -3.0e38f; bi[q] = 0; }
        for (int e = 0; e < NEXP; ++e) {
            float s = S[tid][e];
            if (s > bs[7]) {
                int pos = 7;
#pragma unroll
                for (int q = 6; q >= 0; q--) pos = (s > bs[q]) ? q : pos;
#pragma unroll
                for (int q = 7; q >= 1; q--) {
                    bool sh = (q > pos);
                    bs[q] = sh ? bs[q - 1] : bs[q];
                    bi[q] = sh ? bi[q - 1] : bi[q];
                }
#pragma unroll
                for (int q = 0; q < 8; q++)
                    if (q == pos) { bs[q] = s; bi[q] = e; }
            }
        }
        float m = bs[0], sum = 0.f, ex[8];
#pragma unroll
        for (int q = 0; q < 8; ++q) { ex[q] = expf(bs[q] - m); sum += ex[q]; }
        float inv = 1.f / fmaxf(sum, 1e-8f);
        const int tok_g = tok0 + tid;
#pragma unroll
        for (int q = 0; q < 8; ++q) {
            wgt[tok_g * TOPK + q] = ex[q] * inv;
            sel[tok_g * TOPK + q] = bi[q];
            atomicAdd(&h[bi[q]], 1);
        }
    }
    __syncthreads();
    if (tid < NEXP) {
        int cc = h[tid];
        bh[tid * SBLK + blockIdx.x] = cc;
        if (cc) atomicAdd(&counts[tid], cc);
    }
}

// ============ scan: expert bases + per-expert exclusive block-scan ============
__global__ void scan_kernel(const int* __restrict__ bh, const int* __restrict__ counts,
                            int* __restrict__ bo, float* __restrict__ out) {
    const int e = blockIdx.x, tid = threadIdx.x;   // 128 blocks x 512 thr
    __shared__ int pre[NEXP];
    __shared__ int wsum[8];
    if (tid < NEXP) pre[tid] = counts[tid];
    __syncthreads();
#pragma unroll
    for (int d = 1; d < NEXP; d <<= 1) {
        int o = (tid < NEXP && tid >= d) ? pre[tid - d] : 0;
        __syncthreads();
        if (tid < NEXP) pre[tid] += o;
        __syncthreads();
    }
    const int gb = (e == 0) ? 0 : pre[e - 1];
    if (tid == 0) out[2 * NFLAT + e] = (float)counts[e];

    const int lane = tid & 63, wid = tid >> 6;
    int v = bh[e * SBLK + tid];
    int sc = v;
#pragma unroll
    for (int d = 1; d < 64; d <<= 1) {
        int o = __shfl_up(sc, d);
        sc += (lane >= d) ? o : 0;
    }
    if (lane == 63) wsum[wid] = sc;
    __syncthreads();
    int add = 0;
#pragma unroll
    for (int ww = 0; ww < 8; ww++) add += (ww < wid) ? wsum[ww] : 0;
    bo[e * SBLK + tid] = gb + sc - v + add;
}

// ============ scatter: stable in-block rank via 7 ballots ============
__global__ void scatter_kernel(const int* __restrict__ sel, const float* __restrict__ wgt,
                               const int* __restrict__ bo, float* __restrict__ out) {
    const int tid = threadIdx.x, b = blockIdx.x;
    const int i = b * 256 + tid;
    const int e = sel[i];
    const int lane = tid & 63, wid = tid >> 6;
    unsigned long long m = ~0ull;
#pragma unroll
    for (int bit = 0; bit < 7; bit++) {
        unsigned long long bal = __ballot((e >> bit) & 1);
        m &= ((e >> bit) & 1) ? bal : ~bal;
    }
    unsigned long long lower = (lane == 0) ? 0ull : (~0ull >> (64 - lane));
    int wrank = __popcll(m & lower);

    __shared__ int wh_[4][NEXP];
    ((int*)wh_)[tid] = 0; ((int*)wh_)[tid + 256] = 0;
    __syncthreads();
    if (wrank == 0) wh_[wid][e] = __popcll(m);
    __syncthreads();
    int off = 0;
#pragma unroll
    for (int ww = 0; ww < 4; ww++) off += (ww < wid) ? wh_[ww][e] : 0;

    int pos = bo[e * SBLK + b] + off + wrank;
    out[pos] = wgt[i];
    out[NFLAT + pos] = (float)(i >> 3);
}

extern "C" void kernel_launch(void* const* d_in, const int* in_sizes, int n_in,
                              void* d_out, int out_size, void* d_ws, size_t ws_size,
                              hipStream_t stream) {
    const float* x  = (const float*)d_in[0];
    const float* gw = (const float*)d_in[1];
    float* out = (float*)d_out;
    char*  ws  = (char*)d_ws;

    int*   counts  = (int*)(ws + COUNTS_OFF);
    int*   sel     = (int*)(ws + SEL_OFF);
    float* wgt     = (float*)(ws + WGT_OFF);
    int*   bh      = (int*)(ws + BH_OFF);
    int*   bo      = (int*)(ws + BO_OFF);
    char*  wpk     = ws + WPK_OFF;
    float* partial = (float*)(ws + PART_OFF);

    hipMemsetAsync(counts, 0, NEXP * sizeof(int), stream);

    wsplit_kernel<<<256, 256, 0, stream>>>(gw, wpk);
    gemm_kernel<<<512, 512, 0, stream>>>(x, wpk, partial);
    topk_kernel<<<512, 256, 0, stream>>>(partial, wgt, sel, counts, bh);
    scan_kernel<<<NEXP, 512, 0, stream>>>(bh, counts, bo, out);
    scatter_kernel<<<SBLK, 256, 0, stream>>>(sel, wgt, bo, out);
}